// Round 5
// baseline (42.702 us; speedup 1.0000x reference)
//
#include <hip/hip_runtime.h>
#include <math.h>

#define N_ATOMS 2048
#define FLTS_PER_BATCH (N_ATOMS * 3)   // 6144 floats per batch per tensor

// ws layout:
//   [0..15]                 : int ticket counter
//   [16 .. 16+B*40*4)       : part[B*4][10] f32 partials
//   [then]                  : blocksum[16] f64
#define WS_PART_OFF   16
#define NBLK_B        16

struct Atom { float x, y, z; };   // 12 B, 4-B aligned -> global_load_dwordx3

// ---------------------------------------------------------------------------
// Kernel A: pure streaming. One wave per QUARTER batch (16384 waves).
// NEW in this round: per-lane loads are 12 B dwordx3 atom loads, so every
// VMEM instruction's 64 lanes cover a dense contiguous 768 B block (every
// byte of every touched cacheline consumed by that instruction), instead of
// the previous 48 B-stride float4 pattern (48 sparse lines per instruction).
// 16 independent loads per lane, fully unrolled. No LDS, no barriers.
// ---------------------------------------------------------------------------
__global__ __launch_bounds__(256) void rmsd_partial_kernel(
    const float* __restrict__ yp, const float* __restrict__ yy,
    float* __restrict__ part /* [B*4][10] */, int* __restrict__ counter)
{
    if (blockIdx.x == 0 && threadIdx.x == 0) *counter = 0;

    const int wid  = (blockIdx.x << 2) + (threadIdx.x >> 6);  // global wave id
    const int lane = threadIdx.x & 63;
    const int b    = wid >> 2;        // batch
    const int q    = wid & 3;         // quarter: atoms [q*512, q*512+512)

    const Atom* A  = reinterpret_cast<const Atom*>(yp + (size_t)b * FLTS_PER_BATCH);
    const Atom* Bv = reinterpret_cast<const Atom*>(yy + (size_t)b * FLTS_PER_BATCH);

    // 8 chunks of 64 atoms; lane handles atom q*512 + c*64 + lane.
    Atom pa[8], pb[8];
    #pragma unroll
    for (int c = 0; c < 8; ++c) {
        const int a = q * 512 + c * 64 + lane;
        pa[c] = A[a];
        pb[c] = Bv[a];
    }

    float sxx = 0.f, sxy = 0.f, sxz = 0.f;
    float syx = 0.f, syy = 0.f, syz = 0.f;
    float szx = 0.f, szy = 0.f, szz = 0.f;
    float nrm = 0.f;

    #pragma unroll
    for (int c = 0; c < 8; ++c) {
        const float px = pa[c].x, py = pa[c].y, pz = pa[c].z;
        const float qx = pb[c].x, qy = pb[c].y, qz = pb[c].z;
        sxx += px * qx; sxy += px * qy; sxz += px * qz;
        syx += py * qx; syy += py * qy; syz += py * qz;
        szx += pz * qx; szy += pz * qy; szz += pz * qz;
        nrm += px * px + py * py + pz * pz
             + qx * qx + qy * qy + qz * qz;
    }

    float vals[10] = {sxx, sxy, sxz, syx, syy, syz, szx, szy, szz, nrm};
    #pragma unroll
    for (int k = 0; k < 10; ++k) {
        #pragma unroll
        for (int off = 32; off > 0; off >>= 1)
            vals[k] += __shfl_down(vals[k], off, 64);
    }

    if (lane == 0) {
        float* dst = part + (size_t)wid * 10;
        #pragma unroll
        for (int k = 0; k < 10; ++k) dst[k] = vals[k];
    }
}

// ---------------------------------------------------------------------------
// Kernel B: one batch per THREAD (16 blocks x 256). QCP Newton eigen-solve,
// block reduction, then deterministic last-block ticket does the final
// 16-sum (fixed order) + sqrt. Unchanged from the passing round-3 version.
// ---------------------------------------------------------------------------
__global__ __launch_bounds__(256) void rmsd_eigen_kernel(
    const float* __restrict__ part, int* __restrict__ counter,
    double* __restrict__ blocksum, float* __restrict__ out)
{
    const int t = threadIdx.x;
    const int b = blockIdx.x * 256 + t;   // batch index
    const float* P = part + (size_t)b * 40;

    double S[10];
    #pragma unroll
    for (int k = 0; k < 10; ++k)
        S[k] = (double)P[k] + (double)P[10 + k] + (double)P[20 + k] + (double)P[30 + k];

    const double Sxx = S[0], Sxy = S[1], Sxz = S[2];
    const double Syx = S[3], Syy = S[4], Syz = S[5];
    const double Szx = S[6], Szy = S[7], Szz = S[8];
    const double sqn = S[9];

    const double Sxx2 = Sxx * Sxx, Syy2 = Syy * Syy, Szz2 = Szz * Szz;
    const double Sxy2 = Sxy * Sxy, Syz2 = Syz * Syz, Sxz2 = Sxz * Sxz;
    const double Syx2 = Syx * Syx, Szy2 = Szy * Szy, Szx2 = Szx * Szx;

    const double SyzSzymSyySzz2 = 2.0 * (Syz * Szy - Syy * Szz);
    const double Sxx2Syy2Szz2Syz2Szy2 = Syy2 + Szz2 - Sxx2 + Syz2 + Szy2;

    const double C2 = -2.0 * (Sxx2 + Syy2 + Szz2 + Sxy2 + Syx2 + Sxz2 + Szx2 + Syz2 + Szy2);
    const double C1 = 8.0 * (Sxx * Syz * Szy + Syy * Szx * Sxz + Szz * Sxy * Syx -
                             Sxx * Syy * Szz - Syz * Szx * Sxy - Szy * Syx * Sxz);

    const double SxzpSzx = Sxz + Szx;
    const double SyzpSzy = Syz + Szy;
    const double SxypSyx = Sxy + Syx;
    const double SyzmSzy = Syz - Szy;
    const double SxzmSzx = Sxz - Szx;
    const double SxymSyx = Sxy - Syx;
    const double SxxpSyy = Sxx + Syy;
    const double SxxmSyy = Sxx - Syy;
    const double Sxy2Sxz2Syx2Szx2 = Sxy2 + Sxz2 - Syx2 - Szx2;

    const double C0 =
        Sxy2Sxz2Syx2Szx2 * Sxy2Sxz2Syx2Szx2
        + (Sxx2Syy2Szz2Syz2Szy2 + SyzSzymSyySzz2) * (Sxx2Syy2Szz2Syz2Szy2 - SyzSzymSyySzz2)
        + (-(SxzpSzx) * (SyzmSzy) + (SxymSyx) * (SxxmSyy - Szz)) *
          (-(SxzmSzx) * (SyzpSzy) + (SxymSyx) * (SxxmSyy + Szz))
        + (-(SxzpSzx) * (SyzpSzy) - (SxypSyx) * (SxxpSyy - Szz)) *
          (-(SxzmSzx) * (SyzmSzy) - (SxypSyx) * (SxxpSyy + Szz))
        + (+(SxypSyx) * (SyzpSzy) + (SxzpSzx) * (SxxmSyy + Szz)) *
          (-(SxymSyx) * (SyzmSzy) + (SxzpSzx) * (SxxpSyy + Szz))
        + (+(SxypSyx) * (SyzmSzy) + (SxzmSzx) * (SxxmSyy - Szz)) *
          (-(SxymSyx) * (SyzpSzy) + (SxzmSzx) * (SxxpSyy - Szz));

    double lam = 0.5 * sqn;
    for (int i = 0; i < 100; ++i) {
        const double old = lam;
        const double x2 = lam * lam;
        const double bp = (x2 + C2) * lam;
        const double ap = bp + C1;
        const double den = 2.0 * x2 * lam + bp + ap;
        if (den == 0.0) break;
        lam -= (ap * lam + C0) / den;
        if (fabs(lam - old) < fabs(1e-13 * lam)) break;
    }
    double sd = sqn - 2.0 * lam;

    // deterministic block reduction
    #pragma unroll
    for (int off = 32; off > 0; off >>= 1)
        sd += __shfl_down(sd, off, 64);

    __shared__ double red[4];
    __shared__ int ticket_s;
    if ((t & 63) == 0) red[t >> 6] = sd;
    __syncthreads();

    if (t == 0) {
        blocksum[blockIdx.x] = red[0] + red[1] + red[2] + red[3];
        __threadfence();
        ticket_s = atomicAdd(counter, 1);
    }
    __syncthreads();

    // Last-finishing block sums all 16 block results in FIXED index order
    // -> bitwise-deterministic output regardless of finish order.
    if (ticket_s == NBLK_B - 1 && t == 0) {
        __threadfence();
        volatile double* bs = blocksum;
        double tot = 0.0;
        #pragma unroll
        for (int i = 0; i < NBLK_B; ++i) tot += bs[i];
        out[0] = (float)sqrt(tot / (double)N_ATOMS);
    }
}

extern "C" void kernel_launch(void* const* d_in, const int* in_sizes, int n_in,
                              void* d_out, int out_size, void* d_ws, size_t ws_size,
                              hipStream_t stream) {
    const float* yp = (const float*)d_in[0];
    const float* yy = (const float*)d_in[1];
    float* out = (float*)d_out;
    const int B = in_sizes[0] / FLTS_PER_BATCH;   // 4096

    int*    counter  = (int*)d_ws;
    float*  part     = (float*)((char*)d_ws + WS_PART_OFF);
    double* blocksum = (double*)((char*)d_ws + WS_PART_OFF + (size_t)B * 40 * sizeof(float));

    rmsd_partial_kernel<<<B, 256, 0, stream>>>(yp, yy, part, counter);
    rmsd_eigen_kernel<<<NBLK_B, 256, 0, stream>>>(part, counter, blocksum, out);
}